// Round 4
// baseline (353.876 us; speedup 1.0000x reference)
//
#include <hip/hip_runtime.h>

typedef __bf16 bhalf;
typedef __bf16 bhalf8 __attribute__((ext_vector_type(8)));
typedef __bf16 bhalf4 __attribute__((ext_vector_type(4)));
typedef float f32x4 __attribute__((ext_vector_type(4)));

typedef __attribute__((address_space(1))) const void* gas_p;
typedef __attribute__((address_space(3))) void* las_p;

#define T_SEQ 2048
#define HIDN  2048
#define NQH   32
#define NKVH  8
#define DH    64
#define NQKV  3072

// ---------------- fused prep: cast + both weight transposes, one dispatch ----------------
// blocks [0,4096): cast hidden fp32->bf16
// blocks [4096,10240): transpose+cast w_qkv (R=2048, C=3072)
// blocks [10240,14336): transpose+cast w_out (R=2048, C=2048)
__global__ __launch_bounds__(256) void prep_k(const float* __restrict__ hidden,
                                              const float* __restrict__ w_qkv,
                                              const float* __restrict__ w_out,
                                              bhalf* __restrict__ hid_bf,
                                              bhalf* __restrict__ wqkvT,
                                              bhalf* __restrict__ woutT) {
  __shared__ float tile[32][33];
  int bid = blockIdx.x;
  if (bid < 4096) {
    int i = (bid * 256 + threadIdx.x) * 4;
    float4 v = *(const float4*)(hidden + i);
    bhalf4 o;
    o[0] = (bhalf)v.x; o[1] = (bhalf)v.y; o[2] = (bhalf)v.z; o[3] = (bhalf)v.w;
    *(bhalf4*)(hid_bf + i) = o;
    return;
  }
  const float* in;
  bhalf* out;
  int R, C, bx, by;
  if (bid < 10240) {
    int b2 = bid - 4096;
    in = w_qkv; out = wqkvT; R = HIDN; C = NQKV;
    bx = (b2 % 96) * 32; by = (b2 / 96) * 32;
  } else {
    int b2 = bid - 10240;
    in = w_out; out = woutT; R = HIDN; C = HIDN;
    bx = (b2 % 64) * 32; by = (b2 / 64) * 32;
  }
  int tx = threadIdx.x & 31, ty = threadIdx.x >> 5;
#pragma unroll
  for (int p = 0; p < 4; ++p)
    tile[ty + 8 * p][tx] = in[(size_t)(by + ty + 8 * p) * C + bx + tx];
  __syncthreads();
#pragma unroll
  for (int p = 0; p < 4; ++p)
    out[(size_t)(bx + ty + 8 * p) * R + by + tx] = (bhalf)tile[tx][ty + 8 * p];
}

// ---------------- shared GEMM core: 128(M) x 128(N) tile, BK=64, double-buffered ----------------
// 4 waves in 2x2; wave tile 64x64 (acc 4x4 of 16x16). Per wave-K-step: 32 MFMA,
// 16 ds_read_b128 (0.5 reads/MFMA vs 0.75 in the old 32x64-wave core).
// XOR-swizzled LDS staged via global_load_lds width=16 (pre-swizzled source).
__device__ __forceinline__ void gemm_core(const bhalf* __restrict__ A,
                                          const bhalf* __restrict__ Bt, int K,
                                          int bm, int bn, int tid,
                                          bhalf* As, bhalf* Bs, f32x4 acc[4][4]) {
  int lane = tid & 63, wv = tid >> 6;
  int m16 = lane & 15, q4 = lane >> 4;
  int wm = (wv >> 1) * 64, wn = (wv & 1) * 64;
  int srow = tid >> 3;                         // 0..31
  int scol = ((tid & 7) ^ (srow & 7)) * 8;     // XOR-swizzled source col block
  const bhalf* asrc = A + (size_t)(bm + srow) * K + scol;
  const bhalf* bsrc = Bt + (size_t)(bn + srow) * K + scol;
  bhalf* adst = As + (wv * 8) * 64;
  bhalf* bdst = Bs + (wv * 8) * 64;
  int swz = m16 & 7;

  auto stage = [&](int k0, int sbuf) {
#pragma unroll
    for (int c = 0; c < 4; ++c)
      __builtin_amdgcn_global_load_lds((gas_p)(asrc + (size_t)(c * 32) * K + k0),
                                       (las_p)(adst + sbuf * 8192 + c * 2048), 16, 0, 0);
#pragma unroll
    for (int c = 0; c < 4; ++c)
      __builtin_amdgcn_global_load_lds((gas_p)(bsrc + (size_t)(c * 32) * K + k0),
                                       (las_p)(bdst + sbuf * 8192 + c * 2048), 16, 0, 0);
  };

  stage(0, 0);
  int buf = 0;
  for (int k0 = 0; k0 < K; k0 += 64) {
    __syncthreads();  // drains vmcnt: buf's tile landed (issued one iter ago)
    if (k0 + 64 < K) stage(k0 + 64, buf ^ 1);
    const bhalf* Ab = As + buf * 8192;
    const bhalf* Bb = Bs + buf * 8192;
#pragma unroll
    for (int ks = 0; ks < 2; ++ks) {
      bhalf8 af[4], bf[4];
#pragma unroll
      for (int mi = 0; mi < 4; ++mi)
        af[mi] = *(const bhalf8*)&Ab[(wm + mi * 16 + m16) * 64 + (((ks * 4 + q4) ^ swz) * 8)];
#pragma unroll
      for (int ni = 0; ni < 4; ++ni)
        bf[ni] = *(const bhalf8*)&Bb[(wn + ni * 16 + m16) * 64 + (((ks * 4 + q4) ^ swz) * 8)];
#pragma unroll
      for (int mi = 0; mi < 4; ++mi)
#pragma unroll
        for (int ni = 0; ni < 4; ++ni)
          acc[mi][ni] = __builtin_amdgcn_mfma_f32_16x16x32_bf16(af[mi], bf[ni], acc[mi][ni], 0, 0, 0);
    }
    buf ^= 1;
  }
}

// ---------------- GEMM1 + fused RMSNorm + RoPE + split + cast + V-transpose ----------------
// Block = 128 rows x 2 heads; each wave owns one head (hh = bn/64 + (wv&1)).
// XCD-aware bijective swizzle: 384 blocks = 8 XCDs x 48.
__global__ __launch_bounds__(256) void gemm1_fused_k(const bhalf* __restrict__ A,
                                                     const bhalf* __restrict__ Bt,
                                                     const int* __restrict__ pos,
                                                     const float* __restrict__ qw,
                                                     const float* __restrict__ kw,
                                                     bhalf* __restrict__ qo,
                                                     bhalf* __restrict__ ko,
                                                     bhalf* __restrict__ vt) {
  __shared__ __align__(16) bhalf As[2 * 8192];
  __shared__ __align__(16) bhalf Bs[2 * 8192];
  int tid = threadIdx.x, lane = tid & 63, wv = tid >> 6;
  int m16 = lane & 15, q4 = lane >> 4;
  int orig = blockIdx.x;                      // 384 blocks
  int wgid = (orig & 7) * 48 + (orig >> 3);   // bijective XCD swizzle (384 = 8*48)
  int bx = wgid % 24, by = wgid / 24;
  int bm = by * 128, bn = bx * 128;
  f32x4 zero4 = {0.f, 0.f, 0.f, 0.f};
  f32x4 acc[4][4];
#pragma unroll
  for (int mi = 0; mi < 4; ++mi)
#pragma unroll
    for (int ni = 0; ni < 4; ++ni) acc[mi][ni] = zero4;

  gemm_core(A, Bt, HIDN, bm, bn, tid, As, Bs, acc);

  int r0 = bm + (wv >> 1) * 64;
  int hh = (bn >> 6) + (wv & 1);              // head handled by this wave
  if (hh < 40) {
    float wd[4];
    const float* wptr = (hh < 32) ? qw : kw;
    float wscale = (hh < 32) ? 0.18033688011112042f : 1.0f;  // 0.125*log2(e) for Q
#pragma unroll
    for (int ni = 0; ni < 4; ++ni) wd[ni] = wptr[ni * 16 + m16] * wscale;
    float f0 = exp2f((float)m16 * -0.6228615177913804f);
    float f1 = f0 * 0.001f;  // theta^(-16/32) = 1e-3
#pragma unroll
    for (int mi = 0; mi < 4; ++mi)
#pragma unroll
      for (int r = 0; r < 4; ++r) {
        int trow = r0 + mi * 16 + q4 * 4 + r;
        float x0 = acc[mi][0][r], x1 = acc[mi][1][r], x2 = acc[mi][2][r], x3 = acc[mi][3][r];
        float ss = x0 * x0 + x1 * x1 + x2 * x2 + x3 * x3;
        ss += __shfl_xor(ss, 1);
        ss += __shfl_xor(ss, 2);
        ss += __shfl_xor(ss, 4);
        ss += __shfl_xor(ss, 8);
        float sc = rsqrtf(ss * (1.0f / 64.0f) + 1e-5f);
        float y0 = x0 * sc * wd[0], y1 = x1 * sc * wd[1];
        float y2 = x2 * sc * wd[2], y3 = x3 * sc * wd[3];
        float p = (float)pos[trow];
        float a0 = p * f0, a1 = p * f1;
        float c0 = cosf(a0), s0 = sinf(a0), c1 = cosf(a1), s1 = sinf(a1);
        float o0 = y0 * c0 - y2 * s0, o2 = y2 * c0 + y0 * s0;
        float o1 = y1 * c1 - y3 * s1, o3 = y3 * c1 + y1 * s1;
        bhalf* dst = (hh < 32) ? (qo + (size_t)trow * 2048 + hh * 64 + m16)
                               : (ko + (size_t)trow * 512 + (hh - 32) * 64 + m16);
        dst[0] = (bhalf)o0; dst[16] = (bhalf)o1; dst[32] = (bhalf)o2; dst[48] = (bhalf)o3;
      }
  } else {
    // V head: write directly transposed -> vt[(hh-40)*64 + d][t], packed 4 t's per store
#pragma unroll
    for (int mi = 0; mi < 4; ++mi)
#pragma unroll
      for (int ni = 0; ni < 4; ++ni) {
        int trow0 = r0 + mi * 16 + q4 * 4;
        int d = (hh - 40) * 64 + ni * 16 + m16;
        bhalf4 pk;
        pk[0] = (bhalf)acc[mi][ni][0]; pk[1] = (bhalf)acc[mi][ni][1];
        pk[2] = (bhalf)acc[mi][ni][2]; pk[3] = (bhalf)acc[mi][ni][3];
        *(bhalf4*)(vt + (size_t)d * 2048 + trow0) = pk;
      }
  }
}

// ---------------- GEMM2: plain fp32-out epilogue ----------------
__global__ __launch_bounds__(256) void gemm2_k(const bhalf* __restrict__ A,
                                               const bhalf* __restrict__ Bt,
                                               float* __restrict__ C) {
  __shared__ __align__(16) bhalf As[2 * 8192];
  __shared__ __align__(16) bhalf Bs[2 * 8192];
  int tid = threadIdx.x, lane = tid & 63, wv = tid >> 6;
  int m16 = lane & 15, q4 = lane >> 4;
  int orig = blockIdx.x;                      // 256 blocks
  int wgid = (orig & 7) * 32 + (orig >> 3);   // bijective XCD swizzle (256 = 8*32)
  int bx = wgid & 15, by = wgid >> 4;
  int bm = by * 128, bn = bx * 128;
  f32x4 zero4 = {0.f, 0.f, 0.f, 0.f};
  f32x4 acc[4][4];
#pragma unroll
  for (int mi = 0; mi < 4; ++mi)
#pragma unroll
    for (int ni = 0; ni < 4; ++ni) acc[mi][ni] = zero4;

  gemm_core(A, Bt, HIDN, bm, bn, tid, As, Bs, acc);

  int r0 = bm + (wv >> 1) * 64;
  int c0 = bn + (wv & 1) * 64;
#pragma unroll
  for (int mi = 0; mi < 4; ++mi)
#pragma unroll
    for (int r = 0; r < 4; ++r) {
      size_t base = (size_t)(r0 + mi * 16 + q4 * 4 + r) * 2048 + c0 + m16;
      C[base] = acc[mi][0][r]; C[base + 16] = acc[mi][1][r];
      C[base + 32] = acc[mi][2][r]; C[base + 48] = acc[mi][3][r];
    }
}

// ---------------- flash attention (causal GQA), fixed-max softmax ----------------
// (unchanged from round 3 — verified passing)
__global__ __launch_bounds__(256) void attn_k(const bhalf* __restrict__ q,
                                              const bhalf* __restrict__ k,
                                              const bhalf* __restrict__ vt,
                                              bhalf* __restrict__ o) {
  __shared__ __align__(16) bhalf Kb[2][4096];
  __shared__ __align__(16) bhalf Vb[2][4096];
  __shared__ __align__(16) bhalf Pb[4][16][64];
  int tid = threadIdx.x, lane = tid & 63, w = tid >> 6;
  int h = blockIdx.x, kh = h >> 2;
  int qt = 31 - blockIdx.y;
  int qb = qt * 64;
  int m16 = lane & 15, q4 = lane >> 4;
  int wrow0 = qb + w * 16;

  const bhalf* qp = q + (size_t)(wrow0 + m16) * 2048 + h * 64;
  bhalf8 qf0 = *(const bhalf8*)(qp + q4 * 8);
  bhalf8 qf1 = *(const bhalf8*)(qp + 32 + q4 * 8);

  int srow = tid >> 3;
  int scol = ((tid & 7) ^ (srow & 7)) * 8;
  const bhalf* ksrc = k + (size_t)srow * 512 + kh * 64 + scol;
  const bhalf* vsrc = vt + (size_t)(kh * 64 + srow) * 2048 + scol;
  bhalf* kdst = &Kb[0][0] + w * 512;
  bhalf* vdst = &Vb[0][0] + w * 512;

  auto stage = [&](int c) {
    int buf = c & 1, s0 = c * 64;
#pragma unroll
    for (int j = 0; j < 2; ++j) {
      __builtin_amdgcn_global_load_lds((gas_p)(ksrc + (size_t)(s0 + j * 32) * 512),
                                       (las_p)(kdst + buf * 4096 + j * 2048), 16, 0, 0);
      __builtin_amdgcn_global_load_lds((gas_p)(vsrc + (size_t)(j * 32) * 2048 + s0),
                                       (las_p)(vdst + buf * 4096 + j * 2048), 16, 0, 0);
    }
  };

  f32x4 zero4 = {0.f, 0.f, 0.f, 0.f};
  f32x4 oac[4];
  float psum = 0.f;
#pragma unroll
  for (int ni = 0; ni < 4; ++ni) oac[ni] = zero4;
  int swz = m16 & 7;
  bhalf* prow = &Pb[w][m16][0];
  int woff = (q4 & 1) << 2;

  stage(0);
  for (int c = 0; c <= qt; ++c) {
    __syncthreads();
    if (c < qt) stage(c + 1);
    int buf = c & 1;
    if (c < qt) {
      bhalf8 kf[4][2];
#pragma unroll
      for (int st = 0; st < 4; ++st)
#pragma unroll
        for (int ks = 0; ks < 2; ++ks)
          kf[st][ks] = *(const bhalf8*)&Kb[buf][(st * 16 + m16) * 64 + (((ks * 4 + q4) ^ swz) * 8)];
      f32x4 sv[4];
      __builtin_amdgcn_s_setprio(1);
#pragma unroll
      for (int st = 0; st < 4; ++st) {
        f32x4 t0 = __builtin_amdgcn_mfma_f32_16x16x32_bf16(kf[st][0], qf0, zero4, 0, 0, 0);
        sv[st] = __builtin_amdgcn_mfma_f32_16x16x32_bf16(kf[st][1], qf1, t0, 0, 0, 0);
      }
      __builtin_amdgcn_s_setprio(0);
#pragma unroll
      for (int st = 0; st < 4; ++st) {
        bhalf4 pk;
#pragma unroll
        for (int r = 0; r < 4; ++r) {
          float pe = exp2f(sv[st][r]);
          psum += pe;
          pk[r] = (bhalf)pe;
        }
        *(bhalf4*)(prow + ((((2 * st + (q4 >> 1)) ^ swz) << 3) + woff)) = pk;
      }
      bhalf8 vf[4][2];
#pragma unroll
      for (int ni = 0; ni < 4; ++ni)
#pragma unroll
        for (int ks = 0; ks < 2; ++ks)
          vf[ni][ks] = *(const bhalf8*)&Vb[buf][(ni * 16 + m16) * 64 + (((ks * 4 + q4) ^ swz) * 8)];
      bhalf8 ap0 = *(const bhalf8*)(prow + ((q4 ^ swz) << 3));
      bhalf8 ap1 = *(const bhalf8*)(prow + (((4 + q4) ^ swz) << 3));
      __builtin_amdgcn_s_setprio(1);
#pragma unroll
      for (int ni = 0; ni < 4; ++ni) {
        oac[ni] = __builtin_amdgcn_mfma_f32_16x16x32_bf16(ap0, vf[ni][0], oac[ni], 0, 0, 0);
        oac[ni] = __builtin_amdgcn_mfma_f32_16x16x32_bf16(ap1, vf[ni][1], oac[ni], 0, 0, 0);
      }
      __builtin_amdgcn_s_setprio(0);
    } else {
      bhalf8 kf[4][2];
      f32x4 sv[4];
#pragma unroll
      for (int st = 0; st < 4; ++st)
        if (st <= w) {
#pragma unroll
          for (int ks = 0; ks < 2; ++ks)
            kf[st][ks] = *(const bhalf8*)&Kb[buf][(st * 16 + m16) * 64 + (((ks * 4 + q4) ^ swz) * 8)];
          f32x4 t0 = __builtin_amdgcn_mfma_f32_16x16x32_bf16(kf[st][0], qf0, zero4, 0, 0, 0);
          sv[st] = __builtin_amdgcn_mfma_f32_16x16x32_bf16(kf[st][1], qf1, t0, 0, 0, 0);
        }
      int stwr = (w >= 2) ? 3 : 1;
#pragma unroll
      for (int st = 0; st < 4; ++st) {
        if (st > stwr) continue;
        bhalf4 pk;
#pragma unroll
        for (int r = 0; r < 4; ++r) {
          float pe = 0.f;
          if (st < w) {
            pe = exp2f(sv[st][r]);
          } else if (st == w) {
            pe = (q4 * 4 + r <= m16) ? exp2f(sv[st][r]) : 0.f;
          }
          psum += pe;
          pk[r] = (bhalf)pe;
        }
        *(bhalf4*)(prow + ((((2 * st + (q4 >> 1)) ^ swz) << 3) + woff)) = pk;
      }
      int ksmax = (w >= 2) ? 1 : 0;
      bhalf8 vf[4][2];
#pragma unroll
      for (int ni = 0; ni < 4; ++ni)
#pragma unroll
        for (int ks = 0; ks < 2; ++ks)
          if (ks <= ksmax)
            vf[ni][ks] = *(const bhalf8*)&Vb[buf][(ni * 16 + m16) * 64 + (((ks * 4 + q4) ^ swz) * 8)];
      bhalf8 ap0 = *(const bhalf8*)(prow + ((q4 ^ swz) << 3));
#pragma unroll
      for (int ni = 0; ni < 4; ++ni)
        oac[ni] = __builtin_amdgcn_mfma_f32_16x16x32_bf16(ap0, vf[ni][0], oac[ni], 0, 0, 0);
      if (ksmax) {
        bhalf8 ap1 = *(const bhalf8*)(prow + (((4 + q4) ^ swz) << 3));
#pragma unroll
        for (int ni = 0; ni < 4; ++ni)
          oac[ni] = __builtin_amdgcn_mfma_f32_16x16x32_bf16(ap1, vf[ni][1], oac[ni], 0, 0, 0);
      }
    }
  }
  psum += __shfl_xor(psum, 16);
  psum += __shfl_xor(psum, 32);
  float inv = 1.0f / psum;
  float invr[4];
#pragma unroll
  for (int r = 0; r < 4; ++r) invr[r] = __shfl(inv, q4 * 4 + r);
#pragma unroll
  for (int ni = 0; ni < 4; ++ni)
#pragma unroll
    for (int r = 0; r < 4; ++r) {
      int trow = wrow0 + q4 * 4 + r;
      o[(size_t)trow * 2048 + h * 64 + ni * 16 + m16] = (bhalf)(oac[ni][r] * invr[r]);
    }
}

extern "C" void kernel_launch(void* const* d_in, const int* in_sizes, int n_in,
                              void* d_out, int out_size, void* d_ws, size_t ws_size,
                              hipStream_t stream) {
  const int* positions = (const int*)d_in[0];
  const float* hidden  = (const float*)d_in[1];
  const float* w_qkv   = (const float*)d_in[2];
  const float* w_out   = (const float*)d_in[3];
  const float* q_ln    = (const float*)d_in[4];
  const float* k_ln    = (const float*)d_in[5];
  float* out = (float*)d_out;

  char* wsp = (char*)d_ws;
  bhalf* hid_bf  = (bhalf*)(wsp);                 //  8,388,608 B
  bhalf* wqkvT   = (bhalf*)(wsp + 8388608);       // 12,582,912 B (3072 x 2048)
  bhalf* woutT   = (bhalf*)(wsp + 20971520);      //  8,388,608 B (2048 x 2048)
  bhalf* q_bf    = (bhalf*)(wsp + 29360128);      //  8,388,608 B
  bhalf* k_bf    = (bhalf*)(wsp + 37748736);      //  2,097,152 B
  bhalf* vt_g    = (bhalf*)(wsp + 41943040);      //  2,097,152 B (written by gemm1)
  bhalf* attn_bf = (bhalf*)(wsp + 44040192);      //  8,388,608 B (ends 52.4 MB)

  prep_k<<<14336, 256, 0, stream>>>(hidden, w_qkv, w_out, hid_bf, wqkvT, woutT);
  gemm1_fused_k<<<384, 256, 0, stream>>>(
      hid_bf, wqkvT, positions, q_ln, k_ln, q_bf, k_bf, vt_g);
  attn_k<<<dim3(NQH, 32), 256, 0, stream>>>(q_bf, k_bf, vt_g, attn_bf);
  gemm2_k<<<256, 256, 0, stream>>>(attn_bf, woutT, out);
}

// Round 5
// 352.585 us; speedup vs baseline: 1.0037x; 1.0037x over previous
//
#include <hip/hip_runtime.h>

typedef __bf16 bhalf;
typedef __bf16 bhalf8 __attribute__((ext_vector_type(8)));
typedef __bf16 bhalf4 __attribute__((ext_vector_type(4)));
typedef float f32x4 __attribute__((ext_vector_type(4)));

typedef __attribute__((address_space(1))) const void* gas_p;
typedef __attribute__((address_space(3))) void* las_p;

#define T_SEQ 2048
#define HIDN  2048
#define NQH   32
#define NKVH  8
#define DH    64
#define NQKV  3072

// ---------------- fused prep: cast + both weight transposes, one dispatch ----------------
__global__ __launch_bounds__(256) void prep_k(const float* __restrict__ hidden,
                                              const float* __restrict__ w_qkv,
                                              const float* __restrict__ w_out,
                                              bhalf* __restrict__ hid_bf,
                                              bhalf* __restrict__ wqkvT,
                                              bhalf* __restrict__ woutT) {
  __shared__ float tile[32][33];
  int bid = blockIdx.x;
  if (bid < 4096) {
    int i = (bid * 256 + threadIdx.x) * 4;
    float4 v = *(const float4*)(hidden + i);
    bhalf4 o;
    o[0] = (bhalf)v.x; o[1] = (bhalf)v.y; o[2] = (bhalf)v.z; o[3] = (bhalf)v.w;
    *(bhalf4*)(hid_bf + i) = o;
    return;
  }
  const float* in;
  bhalf* out;
  int R, C, bx, by;
  if (bid < 10240) {
    int b2 = bid - 4096;
    in = w_qkv; out = wqkvT; R = HIDN; C = NQKV;
    bx = (b2 % 96) * 32; by = (b2 / 96) * 32;
  } else {
    int b2 = bid - 10240;
    in = w_out; out = woutT; R = HIDN; C = HIDN;
    bx = (b2 % 64) * 32; by = (b2 / 64) * 32;
  }
  int tx = threadIdx.x & 31, ty = threadIdx.x >> 5;
#pragma unroll
  for (int p = 0; p < 4; ++p)
    tile[ty + 8 * p][tx] = in[(size_t)(by + ty + 8 * p) * C + bx + tx];
  __syncthreads();
#pragma unroll
  for (int p = 0; p < 4; ++p)
    out[(size_t)(bx + ty + 8 * p) * R + by + tx] = (bhalf)tile[tx][ty + 8 * p];
}

#define MFMA_BF16 __builtin_amdgcn_mfma_f32_16x16x32_bf16

// ---- 128x128 GEMM core, m97-faithful: single-buffered 32KB LDS, macro in kernel
// scope, named fragment scalars, constant-indexed acc (no array-through-pointer,
// no runtime buf index -> accumulator stays in AGPRs, no scratch spill).
// Requires in scope: tid, wv, m16, q4, bm, bn, As[8192], Bs[8192], acc[4][4].
#define GEMM_KS(ks)                                                            \
  {                                                                            \
    const int co_ = (((ks) * 4 + q4) ^ swz_) * 8;                              \
    bhalf8 af0 = *(const bhalf8*)&As[(wm_ +  0 + m16) * 64 + co_];             \
    bhalf8 af1 = *(const bhalf8*)&As[(wm_ + 16 + m16) * 64 + co_];             \
    bhalf8 af2 = *(const bhalf8*)&As[(wm_ + 32 + m16) * 64 + co_];             \
    bhalf8 af3 = *(const bhalf8*)&As[(wm_ + 48 + m16) * 64 + co_];             \
    bhalf8 bf0 = *(const bhalf8*)&Bs[(wn_ +  0 + m16) * 64 + co_];             \
    bhalf8 bf1 = *(const bhalf8*)&Bs[(wn_ + 16 + m16) * 64 + co_];             \
    bhalf8 bf2 = *(const bhalf8*)&Bs[(wn_ + 32 + m16) * 64 + co_];             \
    bhalf8 bf3 = *(const bhalf8*)&Bs[(wn_ + 48 + m16) * 64 + co_];             \
    acc[0][0] = MFMA_BF16(af0, bf0, acc[0][0], 0, 0, 0);                       \
    acc[0][1] = MFMA_BF16(af0, bf1, acc[0][1], 0, 0, 0);                       \
    acc[0][2] = MFMA_BF16(af0, bf2, acc[0][2], 0, 0, 0);                       \
    acc[0][3] = MFMA_BF16(af0, bf3, acc[0][3], 0, 0, 0);                       \
    acc[1][0] = MFMA_BF16(af1, bf0, acc[1][0], 0, 0, 0);                       \
    acc[1][1] = MFMA_BF16(af1, bf1, acc[1][1], 0, 0, 0);                       \
    acc[1][2] = MFMA_BF16(af1, bf2, acc[1][2], 0, 0, 0);                       \
    acc[1][3] = MFMA_BF16(af1, bf3, acc[1][3], 0, 0, 0);                       \
    acc[2][0] = MFMA_BF16(af2, bf0, acc[2][0], 0, 0, 0);                       \
    acc[2][1] = MFMA_BF16(af2, bf1, acc[2][1], 0, 0, 0);                       \
    acc[2][2] = MFMA_BF16(af2, bf2, acc[2][2], 0, 0, 0);                       \
    acc[2][3] = MFMA_BF16(af2, bf3, acc[2][3], 0, 0, 0);                       \
    acc[3][0] = MFMA_BF16(af3, bf0, acc[3][0], 0, 0, 0);                       \
    acc[3][1] = MFMA_BF16(af3, bf1, acc[3][1], 0, 0, 0);                       \
    acc[3][2] = MFMA_BF16(af3, bf2, acc[3][2], 0, 0, 0);                       \
    acc[3][3] = MFMA_BF16(af3, bf3, acc[3][3], 0, 0, 0);                       \
  }

#define GEMM_CORE_128(Aptr, Bptr, KK)                                          \
  {                                                                            \
    const int srow_ = tid >> 3;                                                \
    const int scol_ = ((tid & 7) ^ (srow_ & 7)) * 8;                           \
    const bhalf* asrc_ = (Aptr) + (size_t)(bm + srow_) * (KK) + scol_;         \
    const bhalf* bsrc_ = (Bptr) + (size_t)(bn + srow_) * (KK) + scol_;         \
    bhalf* adst_ = As + (wv * 8) * 64;                                         \
    bhalf* bdst_ = Bs + (wv * 8) * 64;                                         \
    const int swz_ = m16 & 7;                                                  \
    const int wm_ = (wv >> 1) * 64, wn_ = (wv & 1) * 64;                       \
    for (int k0 = 0; k0 < (KK); k0 += 64) {                                    \
      __syncthreads(); /* previous iteration's LDS reads complete */           \
      _Pragma("unroll")                                                        \
      for (int c = 0; c < 4; ++c) {                                            \
        __builtin_amdgcn_global_load_lds(                                      \
            (gas_p)(asrc_ + (size_t)(c * 32) * (KK) + k0),                     \
            (las_p)(adst_ + c * 2048), 16, 0, 0);                              \
        __builtin_amdgcn_global_load_lds(                                      \
            (gas_p)(bsrc_ + (size_t)(c * 32) * (KK) + k0),                     \
            (las_p)(bdst_ + c * 2048), 16, 0, 0);                              \
      }                                                                        \
      __syncthreads(); /* vmcnt drained before barrier: tile visible */        \
      GEMM_KS(0)                                                               \
      GEMM_KS(1)                                                               \
    }                                                                          \
  }

// ---------------- GEMM1 + fused RMSNorm + RoPE + split + cast + V-transpose ----------------
// Block 128x128 = 128 rows x 2 heads; wave (2x2) owns 64x64 = one head's rows.
__global__ __launch_bounds__(256) void gemm1_fused_k(const bhalf* __restrict__ A,
                                                     const bhalf* __restrict__ Bt,
                                                     const int* __restrict__ pos,
                                                     const float* __restrict__ qw,
                                                     const float* __restrict__ kw,
                                                     bhalf* __restrict__ qo,
                                                     bhalf* __restrict__ ko,
                                                     bhalf* __restrict__ vt) {
  __shared__ __align__(16) bhalf As[8192];
  __shared__ __align__(16) bhalf Bs[8192];
  int tid = threadIdx.x, lane = tid & 63, wv = tid >> 6;
  int m16 = lane & 15, q4 = lane >> 4;
  int orig = blockIdx.x;                      // 384 blocks
  int wgid = (orig & 7) * 48 + (orig >> 3);   // bijective XCD swizzle (384 = 8*48)
  int bx = wgid % 24, by = wgid / 24;
  int bm = by * 128, bn = bx * 128;
  f32x4 zero4 = {0.f, 0.f, 0.f, 0.f};
  f32x4 acc[4][4];
#pragma unroll
  for (int mi = 0; mi < 4; ++mi)
#pragma unroll
    for (int ni = 0; ni < 4; ++ni) acc[mi][ni] = zero4;

  GEMM_CORE_128(A, Bt, HIDN)

  int r0 = bm + (wv >> 1) * 64;
  int hh = (bn >> 6) + (wv & 1);              // head handled by this wave
  if (hh < 40) {
    float wd[4];
    const float* wptr = (hh < 32) ? qw : kw;
    float wscale = (hh < 32) ? 0.18033688011112042f : 1.0f;  // 0.125*log2(e) for Q
#pragma unroll
    for (int ni = 0; ni < 4; ++ni) wd[ni] = wptr[ni * 16 + m16] * wscale;
    float f0 = exp2f((float)m16 * -0.6228615177913804f);
    float f1 = f0 * 0.001f;  // theta^(-16/32) = 1e-3
#pragma unroll
    for (int mi = 0; mi < 4; ++mi)
#pragma unroll
      for (int r = 0; r < 4; ++r) {
        int trow = r0 + mi * 16 + q4 * 4 + r;
        float x0 = acc[mi][0][r], x1 = acc[mi][1][r], x2 = acc[mi][2][r], x3 = acc[mi][3][r];
        float ss = x0 * x0 + x1 * x1 + x2 * x2 + x3 * x3;
        ss += __shfl_xor(ss, 1);
        ss += __shfl_xor(ss, 2);
        ss += __shfl_xor(ss, 4);
        ss += __shfl_xor(ss, 8);
        float sc = rsqrtf(ss * (1.0f / 64.0f) + 1e-5f);
        float y0 = x0 * sc * wd[0], y1 = x1 * sc * wd[1];
        float y2 = x2 * sc * wd[2], y3 = x3 * sc * wd[3];
        float p = (float)pos[trow];
        float a0 = p * f0, a1 = p * f1;
        float c0 = cosf(a0), s0 = sinf(a0), c1 = cosf(a1), s1 = sinf(a1);
        float o0 = y0 * c0 - y2 * s0, o2 = y2 * c0 + y0 * s0;
        float o1 = y1 * c1 - y3 * s1, o3 = y3 * c1 + y1 * s1;
        bhalf* dst = (hh < 32) ? (qo + (size_t)trow * 2048 + hh * 64 + m16)
                               : (ko + (size_t)trow * 512 + (hh - 32) * 64 + m16);
        dst[0] = (bhalf)o0; dst[16] = (bhalf)o1; dst[32] = (bhalf)o2; dst[48] = (bhalf)o3;
      }
  } else {
    // V head: write directly transposed -> vt[(hh-40)*64 + d][t], 4 t's per store
#pragma unroll
    for (int mi = 0; mi < 4; ++mi)
#pragma unroll
      for (int ni = 0; ni < 4; ++ni) {
        int trow0 = r0 + mi * 16 + q4 * 4;
        int d = (hh - 40) * 64 + ni * 16 + m16;
        bhalf4 pk;
        pk[0] = (bhalf)acc[mi][ni][0]; pk[1] = (bhalf)acc[mi][ni][1];
        pk[2] = (bhalf)acc[mi][ni][2]; pk[3] = (bhalf)acc[mi][ni][3];
        *(bhalf4*)(vt + (size_t)d * 2048 + trow0) = pk;
      }
  }
}

// ---------------- GEMM2: plain fp32-out epilogue ----------------
__global__ __launch_bounds__(256) void gemm2_k(const bhalf* __restrict__ A,
                                               const bhalf* __restrict__ Bt,
                                               float* __restrict__ C) {
  __shared__ __align__(16) bhalf As[8192];
  __shared__ __align__(16) bhalf Bs[8192];
  int tid = threadIdx.x, lane = tid & 63, wv = tid >> 6;
  int m16 = lane & 15, q4 = lane >> 4;
  int orig = blockIdx.x;                      // 256 blocks
  int wgid = (orig & 7) * 32 + (orig >> 3);   // bijective XCD swizzle (256 = 8*32)
  int bx = wgid & 15, by = wgid >> 4;
  int bm = by * 128, bn = bx * 128;
  f32x4 zero4 = {0.f, 0.f, 0.f, 0.f};
  f32x4 acc[4][4];
#pragma unroll
  for (int mi = 0; mi < 4; ++mi)
#pragma unroll
    for (int ni = 0; ni < 4; ++ni) acc[mi][ni] = zero4;

  GEMM_CORE_128(A, Bt, HIDN)

  int r0 = bm + (wv >> 1) * 64;
  int c0 = bn + (wv & 1) * 64;
#pragma unroll
  for (int mi = 0; mi < 4; ++mi)
#pragma unroll
    for (int r = 0; r < 4; ++r) {
      size_t base = (size_t)(r0 + mi * 16 + q4 * 4 + r) * 2048 + c0 + m16;
      C[base] = acc[mi][0][r]; C[base + 16] = acc[mi][1][r];
      C[base + 32] = acc[mi][2][r]; C[base + 48] = acc[mi][3][r];
    }
}

// ---------------- flash attention (causal GQA), fixed-max softmax ----------------
// (unchanged — verified passing at 49.5 us)
__global__ __launch_bounds__(256) void attn_k(const bhalf* __restrict__ q,
                                              const bhalf* __restrict__ k,
                                              const bhalf* __restrict__ vt,
                                              bhalf* __restrict__ o) {
  __shared__ __align__(16) bhalf Kb[2][4096];
  __shared__ __align__(16) bhalf Vb[2][4096];
  __shared__ __align__(16) bhalf Pb[4][16][64];
  int tid = threadIdx.x, lane = tid & 63, w = tid >> 6;
  int h = blockIdx.x, kh = h >> 2;
  int qt = 31 - blockIdx.y;
  int qb = qt * 64;
  int m16 = lane & 15, q4 = lane >> 4;
  int wrow0 = qb + w * 16;

  const bhalf* qp = q + (size_t)(wrow0 + m16) * 2048 + h * 64;
  bhalf8 qf0 = *(const bhalf8*)(qp + q4 * 8);
  bhalf8 qf1 = *(const bhalf8*)(qp + 32 + q4 * 8);

  int srow = tid >> 3;
  int scol = ((tid & 7) ^ (srow & 7)) * 8;
  const bhalf* ksrc = k + (size_t)srow * 512 + kh * 64 + scol;
  const bhalf* vsrc = vt + (size_t)(kh * 64 + srow) * 2048 + scol;
  bhalf* kdst = &Kb[0][0] + w * 512;
  bhalf* vdst = &Vb[0][0] + w * 512;

  auto stage = [&](int c) {
    int buf = c & 1, s0 = c * 64;
#pragma unroll
    for (int j = 0; j < 2; ++j) {
      __builtin_amdgcn_global_load_lds((gas_p)(ksrc + (size_t)(s0 + j * 32) * 512),
                                       (las_p)(kdst + buf * 4096 + j * 2048), 16, 0, 0);
      __builtin_amdgcn_global_load_lds((gas_p)(vsrc + (size_t)(j * 32) * 2048 + s0),
                                       (las_p)(vdst + buf * 4096 + j * 2048), 16, 0, 0);
    }
  };

  f32x4 zero4 = {0.f, 0.f, 0.f, 0.f};
  f32x4 oac[4];
  float psum = 0.f;
#pragma unroll
  for (int ni = 0; ni < 4; ++ni) oac[ni] = zero4;
  int swz = m16 & 7;
  bhalf* prow = &Pb[w][m16][0];
  int woff = (q4 & 1) << 2;

  stage(0);
  for (int c = 0; c <= qt; ++c) {
    __syncthreads();
    if (c < qt) stage(c + 1);
    int buf = c & 1;
    if (c < qt) {
      bhalf8 kf[4][2];
#pragma unroll
      for (int st = 0; st < 4; ++st)
#pragma unroll
        for (int ks = 0; ks < 2; ++ks)
          kf[st][ks] = *(const bhalf8*)&Kb[buf][(st * 16 + m16) * 64 + (((ks * 4 + q4) ^ swz) * 8)];
      f32x4 sv[4];
      __builtin_amdgcn_s_setprio(1);
#pragma unroll
      for (int st = 0; st < 4; ++st) {
        f32x4 t0 = __builtin_amdgcn_mfma_f32_16x16x32_bf16(kf[st][0], qf0, zero4, 0, 0, 0);
        sv[st] = __builtin_amdgcn_mfma_f32_16x16x32_bf16(kf[st][1], qf1, t0, 0, 0, 0);
      }
      __builtin_amdgcn_s_setprio(0);
#pragma unroll
      for (int st = 0; st < 4; ++st) {
        bhalf4 pk;
#pragma unroll
        for (int r = 0; r < 4; ++r) {
          float pe = exp2f(sv[st][r]);
          psum += pe;
          pk[r] = (bhalf)pe;
        }
        *(bhalf4*)(prow + ((((2 * st + (q4 >> 1)) ^ swz) << 3) + woff)) = pk;
      }
      bhalf8 vf[4][2];
#pragma unroll
      for (int ni = 0; ni < 4; ++ni)
#pragma unroll
        for (int ks = 0; ks < 2; ++ks)
          vf[ni][ks] = *(const bhalf8*)&Vb[buf][(ni * 16 + m16) * 64 + (((ks * 4 + q4) ^ swz) * 8)];
      bhalf8 ap0 = *(const bhalf8*)(prow + ((q4 ^ swz) << 3));
      bhalf8 ap1 = *(const bhalf8*)(prow + (((4 + q4) ^ swz) << 3));
      __builtin_amdgcn_s_setprio(1);
#pragma unroll
      for (int ni = 0; ni < 4; ++ni) {
        oac[ni] = __builtin_amdgcn_mfma_f32_16x16x32_bf16(ap0, vf[ni][0], oac[ni], 0, 0, 0);
        oac[ni] = __builtin_amdgcn_mfma_f32_16x16x32_bf16(ap1, vf[ni][1], oac[ni], 0, 0, 0);
      }
      __builtin_amdgcn_s_setprio(0);
    } else {
      bhalf8 kf[4][2];
      f32x4 sv[4];
#pragma unroll
      for (int st = 0; st < 4; ++st)
        if (st <= w) {
#pragma unroll
          for (int ks = 0; ks < 2; ++ks)
            kf[st][ks] = *(const bhalf8*)&Kb[buf][(st * 16 + m16) * 64 + (((ks * 4 + q4) ^ swz) * 8)];
          f32x4 t0 = __builtin_amdgcn_mfma_f32_16x16x32_bf16(kf[st][0], qf0, zero4, 0, 0, 0);
          sv[st] = __builtin_amdgcn_mfma_f32_16x16x32_bf16(kf[st][1], qf1, t0, 0, 0, 0);
        }
      int stwr = (w >= 2) ? 3 : 1;
#pragma unroll
      for (int st = 0; st < 4; ++st) {
        if (st > stwr) continue;
        bhalf4 pk;
#pragma unroll
        for (int r = 0; r < 4; ++r) {
          float pe = 0.f;
          if (st < w) {
            pe = exp2f(sv[st][r]);
          } else if (st == w) {
            pe = (q4 * 4 + r <= m16) ? exp2f(sv[st][r]) : 0.f;
          }
          psum += pe;
          pk[r] = (bhalf)pe;
        }
        *(bhalf4*)(prow + ((((2 * st + (q4 >> 1)) ^ swz) << 3) + woff)) = pk;
      }
      int ksmax = (w >= 2) ? 1 : 0;
      bhalf8 vf[4][2];
#pragma unroll
      for (int ni = 0; ni < 4; ++ni)
#pragma unroll
        for (int ks = 0; ks < 2; ++ks)
          if (ks <= ksmax)
            vf[ni][ks] = *(const bhalf8*)&Vb[buf][(ni * 16 + m16) * 64 + (((ks * 4 + q4) ^ swz) * 8)];
      bhalf8 ap0 = *(const bhalf8*)(prow + ((q4 ^ swz) << 3));
#pragma unroll
      for (int ni = 0; ni < 4; ++ni)
        oac[ni] = __builtin_amdgcn_mfma_f32_16x16x32_bf16(ap0, vf[ni][0], oac[ni], 0, 0, 0);
      if (ksmax) {
        bhalf8 ap1 = *(const bhalf8*)(prow + (((4 + q4) ^ swz) << 3));
#pragma unroll
        for (int ni = 0; ni < 4; ++ni)
          oac[ni] = __builtin_amdgcn_mfma_f32_16x16x32_bf16(ap1, vf[ni][1], oac[ni], 0, 0, 0);
      }
    }
  }
  psum += __shfl_xor(psum, 16);
  psum += __shfl_xor(psum, 32);
  float inv = 1.0f / psum;
  float invr[4];
#pragma unroll
  for (int r = 0; r < 4; ++r) invr[r] = __shfl(inv, q4 * 4 + r);
#pragma unroll
  for (int ni = 0; ni < 4; ++ni)
#pragma unroll
    for (int r = 0; r < 4; ++r) {
      int trow = wrow0 + q4 * 4 + r;
      o[(size_t)trow * 2048 + h * 64 + ni * 16 + m16] = (bhalf)(oac[ni][r] * invr[r]);
    }
}

extern "C" void kernel_launch(void* const* d_in, const int* in_sizes, int n_in,
                              void* d_out, int out_size, void* d_ws, size_t ws_size,
                              hipStream_t stream) {
  const int* positions = (const int*)d_in[0];
  const float* hidden  = (const float*)d_in[1];
  const float* w_qkv   = (const float*)d_in[2];
  const float* w_out   = (const float*)d_in[3];
  const float* q_ln    = (const float*)d_in[4];
  const float* k_ln    = (const float*)d_in[5];
  float* out = (float*)d_out;

  char* wsp = (char*)d_ws;
  bhalf* hid_bf  = (bhalf*)(wsp);                 //  8,388,608 B
  bhalf* wqkvT   = (bhalf*)(wsp + 8388608);       // 12,582,912 B (3072 x 2048)
  bhalf* woutT   = (bhalf*)(wsp + 20971520);      //  8,388,608 B (2048 x 2048)
  bhalf* q_bf    = (bhalf*)(wsp + 29360128);      //  8,388,608 B
  bhalf* k_bf    = (bhalf*)(wsp + 37748736);      //  2,097,152 B
  bhalf* vt_g    = (bhalf*)(wsp + 41943040);      //  2,097,152 B (written by gemm1)
  bhalf* attn_bf = (bhalf*)(wsp + 44040192);      //  8,388,608 B (ends 52.4 MB)

  prep_k<<<14336, 256, 0, stream>>>(hidden, w_qkv, w_out, hid_bf, wqkvT, woutT);
  gemm1_fused_k<<<384, 256, 0, stream>>>(
      hid_bf, wqkvT, positions, q_ln, k_ln, q_bf, k_bf, vt_g);
  attn_k<<<dim3(NQH, 32), 256, 0, stream>>>(q_bf, k_bf, vt_g, attn_bf);
  gemm2_k<<<256, 256, 0, stream>>>(attn_bf, woutT, out);
}

// Round 6
// 223.080 us; speedup vs baseline: 1.5863x; 1.5805x over previous
//
#include <hip/hip_runtime.h>

typedef __bf16 bhalf;
typedef __bf16 bhalf8 __attribute__((ext_vector_type(8)));
typedef __bf16 bhalf4 __attribute__((ext_vector_type(4)));
typedef float f32x4 __attribute__((ext_vector_type(4)));

typedef __attribute__((address_space(1))) const void* gas_p;
typedef __attribute__((address_space(3))) void* las_p;

#define T_SEQ 2048
#define HIDN  2048
#define NQH   32
#define NKVH  8
#define DH    64
#define NQKV  3072

// ---------------- fused prep: cast + weight transposes + RoPE table ----------------
// blocks [0,4096): cast hidden fp32->bf16
// blocks [4096,10240): transpose+cast w_qkv
// blocks [10240,14336): transpose+cast w_out
// blocks [14336,14464): RoPE cos/sin table  rope[t][j] = {cos(a0),sin(a0),cos(a1),sin(a1)}
__global__ __launch_bounds__(256) void prep_k(const float* __restrict__ hidden,
                                              const float* __restrict__ w_qkv,
                                              const float* __restrict__ w_out,
                                              const int* __restrict__ pos,
                                              bhalf* __restrict__ hid_bf,
                                              bhalf* __restrict__ wqkvT,
                                              bhalf* __restrict__ woutT,
                                              float* __restrict__ rope) {
  __shared__ float tile[32][33];
  int bid = blockIdx.x;
  if (bid < 4096) {
    int i = (bid * 256 + threadIdx.x) * 4;
    float4 v = *(const float4*)(hidden + i);
    bhalf4 o;
    o[0] = (bhalf)v.x; o[1] = (bhalf)v.y; o[2] = (bhalf)v.z; o[3] = (bhalf)v.w;
    *(bhalf4*)(hid_bf + i) = o;
    return;
  }
  if (bid >= 14336) {
    int gid = (bid - 14336) * 256 + threadIdx.x;   // 32768 = 2048 t x 16 j
    int t = gid >> 4, j = gid & 15;
    float p = (float)pos[t];
    float f0 = exp2f((float)j * -0.6228615177913804f);  // theta^(-j/32)
    float a0 = p * f0, a1 = p * f0 * 0.001f;            // theta^(-16/32) = 1e-3
    float4 cs = {cosf(a0), sinf(a0), cosf(a1), sinf(a1)};
    *(float4*)(rope + (size_t)gid * 4) = cs;
    return;
  }
  const float* in;
  bhalf* out;
  int R, C, bx, by;
  if (bid < 10240) {
    int b2 = bid - 4096;
    in = w_qkv; out = wqkvT; R = HIDN; C = NQKV;
    bx = (b2 % 96) * 32; by = (b2 / 96) * 32;
  } else {
    int b2 = bid - 10240;
    in = w_out; out = woutT; R = HIDN; C = HIDN;
    bx = (b2 % 64) * 32; by = (b2 / 64) * 32;
  }
  int tx = threadIdx.x & 31, ty = threadIdx.x >> 5;
#pragma unroll
  for (int p = 0; p < 4; ++p)
    tile[ty + 8 * p][tx] = in[(size_t)(by + ty + 8 * p) * C + bx + tx];
  __syncthreads();
#pragma unroll
  for (int p = 0; p < 4; ++p)
    out[(size_t)(bx + ty + 8 * p) * R + by + tx] = (bhalf)tile[tx][ty + 8 * p];
}

#define MFMA_BF16 __builtin_amdgcn_mfma_f32_16x16x32_bf16

// ---- 128x128 GEMM core (m97 structure): single-buffered 32KB LDS, 2 barriers/K-step,
// wave (2x2) tile 64x64, acc[4][4], global_load_lds width=16, XOR-swizzled LDS.
#define GEMM_KS(ks)                                                            \
  {                                                                            \
    const int co_ = (((ks) * 4 + q4) ^ swz_) * 8;                              \
    bhalf8 af0 = *(const bhalf8*)&As[(wm_ +  0 + m16) * 64 + co_];             \
    bhalf8 af1 = *(const bhalf8*)&As[(wm_ + 16 + m16) * 64 + co_];             \
    bhalf8 af2 = *(const bhalf8*)&As[(wm_ + 32 + m16) * 64 + co_];             \
    bhalf8 af3 = *(const bhalf8*)&As[(wm_ + 48 + m16) * 64 + co_];             \
    bhalf8 bf0 = *(const bhalf8*)&Bs[(wn_ +  0 + m16) * 64 + co_];             \
    bhalf8 bf1 = *(const bhalf8*)&Bs[(wn_ + 16 + m16) * 64 + co_];             \
    bhalf8 bf2 = *(const bhalf8*)&Bs[(wn_ + 32 + m16) * 64 + co_];             \
    bhalf8 bf3 = *(const bhalf8*)&Bs[(wn_ + 48 + m16) * 64 + co_];             \
    acc[0][0] = MFMA_BF16(af0, bf0, acc[0][0], 0, 0, 0);                       \
    acc[0][1] = MFMA_BF16(af0, bf1, acc[0][1], 0, 0, 0);                       \
    acc[0][2] = MFMA_BF16(af0, bf2, acc[0][2], 0, 0, 0);                       \
    acc[0][3] = MFMA_BF16(af0, bf3, acc[0][3], 0, 0, 0);                       \
    acc[1][0] = MFMA_BF16(af1, bf0, acc[1][0], 0, 0, 0);                       \
    acc[1][1] = MFMA_BF16(af1, bf1, acc[1][1], 0, 0, 0);                       \
    acc[1][2] = MFMA_BF16(af1, bf2, acc[1][2], 0, 0, 0);                       \
    acc[1][3] = MFMA_BF16(af1, bf3, acc[1][3], 0, 0, 0);                       \
    acc[2][0] = MFMA_BF16(af2, bf0, acc[2][0], 0, 0, 0);                       \
    acc[2][1] = MFMA_BF16(af2, bf1, acc[2][1], 0, 0, 0);                       \
    acc[2][2] = MFMA_BF16(af2, bf2, acc[2][2], 0, 0, 0);                       \
    acc[2][3] = MFMA_BF16(af2, bf3, acc[2][3], 0, 0, 0);                       \
    acc[3][0] = MFMA_BF16(af3, bf0, acc[3][0], 0, 0, 0);                       \
    acc[3][1] = MFMA_BF16(af3, bf1, acc[3][1], 0, 0, 0);                       \
    acc[3][2] = MFMA_BF16(af3, bf2, acc[3][2], 0, 0, 0);                       \
    acc[3][3] = MFMA_BF16(af3, bf3, acc[3][3], 0, 0, 0);                       \
  }

#define GEMM_CORE_128(Aptr, Bptr, KK)                                          \
  {                                                                            \
    const int srow_ = tid >> 3;                                                \
    const int scol_ = ((tid & 7) ^ (srow_ & 7)) * 8;                           \
    const bhalf* asrc_ = (Aptr) + (size_t)(bm + srow_) * (KK) + scol_;         \
    const bhalf* bsrc_ = (Bptr) + (size_t)(bn + srow_) * (KK) + scol_;         \
    bhalf* adst_ = As + (wv * 8) * 64;                                         \
    bhalf* bdst_ = Bs + (wv * 8) * 64;                                         \
    const int swz_ = m16 & 7;                                                  \
    const int wm_ = (wv >> 1) * 64, wn_ = (wv & 1) * 64;                       \
    for (int k0 = 0; k0 < (KK); k0 += 64) {                                    \
      __syncthreads(); /* previous iteration's LDS reads complete */           \
      _Pragma("unroll")                                                        \
      for (int c = 0; c < 4; ++c) {                                            \
        __builtin_amdgcn_global_load_lds(                                      \
            (gas_p)(asrc_ + (size_t)(c * 32) * (KK) + k0),                     \
            (las_p)(adst_ + c * 2048), 16, 0, 0);                              \
        __builtin_amdgcn_global_load_lds(                                      \
            (gas_p)(bsrc_ + (size_t)(c * 32) * (KK) + k0),                     \
            (las_p)(bdst_ + c * 2048), 16, 0, 0);                              \
      }                                                                        \
      __syncthreads(); /* vmcnt drained before barrier: tile visible */        \
      GEMM_KS(0)                                                               \
      GEMM_KS(1)                                                               \
    }                                                                          \
  }

// ---------------- GEMM1 + fused RMSNorm + RoPE(table) + split + cast + V-transpose --------
// Block 128x128 = 128 rows x 2 heads; wave (2x2) owns 64x64 = one head's rows.
// NO libm calls in the epilogue (RoPE via table) -> acc can live in AGPRs.
__global__ __launch_bounds__(256, 1) void gemm1_fused_k(const bhalf* __restrict__ A,
                                                        const bhalf* __restrict__ Bt,
                                                        const float* __restrict__ rope,
                                                        const float* __restrict__ qw,
                                                        const float* __restrict__ kw,
                                                        bhalf* __restrict__ qo,
                                                        bhalf* __restrict__ ko,
                                                        bhalf* __restrict__ vt) {
  __shared__ __align__(16) bhalf As[8192];
  __shared__ __align__(16) bhalf Bs[8192];
  int tid = threadIdx.x, lane = tid & 63, wv = tid >> 6;
  int m16 = lane & 15, q4 = lane >> 4;
  int orig = blockIdx.x;                      // 384 blocks
  int wgid = (orig & 7) * 48 + (orig >> 3);   // bijective XCD swizzle (384 = 8*48)
  int bx = wgid % 24, by = wgid / 24;
  int bm = by * 128, bn = bx * 128;
  f32x4 zero4 = {0.f, 0.f, 0.f, 0.f};
  f32x4 acc[4][4];
#pragma unroll
  for (int mi = 0; mi < 4; ++mi)
#pragma unroll
    for (int ni = 0; ni < 4; ++ni) acc[mi][ni] = zero4;

  GEMM_CORE_128(A, Bt, HIDN)

  int r0 = bm + (wv >> 1) * 64;
  int hh = (bn >> 6) + (wv & 1);              // head handled by this wave
  if (hh < 40) {
    float wd[4];
    const float* wptr = (hh < 32) ? qw : kw;
    float wscale = (hh < 32) ? 0.18033688011112042f : 1.0f;  // 0.125*log2(e) for Q
#pragma unroll
    for (int ni = 0; ni < 4; ++ni) wd[ni] = wptr[ni * 16 + m16] * wscale;
#pragma unroll
    for (int mi = 0; mi < 4; ++mi)
#pragma unroll
      for (int r = 0; r < 4; ++r) {
        int trow = r0 + mi * 16 + q4 * 4 + r;
        float x0 = acc[mi][0][r], x1 = acc[mi][1][r], x2 = acc[mi][2][r], x3 = acc[mi][3][r];
        float ss = x0 * x0 + x1 * x1 + x2 * x2 + x3 * x3;
        ss += __shfl_xor(ss, 1);
        ss += __shfl_xor(ss, 2);
        ss += __shfl_xor(ss, 4);
        ss += __shfl_xor(ss, 8);
        float sc = rsqrtf(ss * (1.0f / 64.0f) + 1e-5f);
        float y0 = x0 * sc * wd[0], y1 = x1 * sc * wd[1];
        float y2 = x2 * sc * wd[2], y3 = x3 * sc * wd[3];
        float4 cs = *(const float4*)(rope + ((size_t)trow * 16 + m16) * 4);
        float o0 = y0 * cs.x - y2 * cs.y, o2 = y2 * cs.x + y0 * cs.y;
        float o1 = y1 * cs.z - y3 * cs.w, o3 = y3 * cs.z + y1 * cs.w;
        bhalf* dst = (hh < 32) ? (qo + (size_t)trow * 2048 + hh * 64 + m16)
                               : (ko + (size_t)trow * 512 + (hh - 32) * 64 + m16);
        dst[0] = (bhalf)o0; dst[16] = (bhalf)o1; dst[32] = (bhalf)o2; dst[48] = (bhalf)o3;
      }
  } else {
    // V head: write directly transposed -> vt[(hh-40)*64 + d][t], 4 t's per store
#pragma unroll
    for (int mi = 0; mi < 4; ++mi)
#pragma unroll
      for (int ni = 0; ni < 4; ++ni) {
        int trow0 = r0 + mi * 16 + q4 * 4;
        int d = (hh - 40) * 64 + ni * 16 + m16;
        bhalf4 pk;
        pk[0] = (bhalf)acc[mi][ni][0]; pk[1] = (bhalf)acc[mi][ni][1];
        pk[2] = (bhalf)acc[mi][ni][2]; pk[3] = (bhalf)acc[mi][ni][3];
        *(bhalf4*)(vt + (size_t)d * 2048 + trow0) = pk;
      }
  }
}

// ---------------- GEMM2: plain fp32-out epilogue ----------------
__global__ __launch_bounds__(256, 1) void gemm2_k(const bhalf* __restrict__ A,
                                                  const bhalf* __restrict__ Bt,
                                                  float* __restrict__ C) {
  __shared__ __align__(16) bhalf As[8192];
  __shared__ __align__(16) bhalf Bs[8192];
  int tid = threadIdx.x, lane = tid & 63, wv = tid >> 6;
  int m16 = lane & 15, q4 = lane >> 4;
  int orig = blockIdx.x;                      // 256 blocks
  int wgid = (orig & 7) * 32 + (orig >> 3);   // bijective XCD swizzle (256 = 8*32)
  int bx = wgid & 15, by = wgid >> 4;
  int bm = by * 128, bn = bx * 128;
  f32x4 zero4 = {0.f, 0.f, 0.f, 0.f};
  f32x4 acc[4][4];
#pragma unroll
  for (int mi = 0; mi < 4; ++mi)
#pragma unroll
    for (int ni = 0; ni < 4; ++ni) acc[mi][ni] = zero4;

  GEMM_CORE_128(A, Bt, HIDN)

  int r0 = bm + (wv >> 1) * 64;
  int c0 = bn + (wv & 1) * 64;
#pragma unroll
  for (int mi = 0; mi < 4; ++mi)
#pragma unroll
    for (int r = 0; r < 4; ++r) {
      size_t base = (size_t)(r0 + mi * 16 + q4 * 4 + r) * 2048 + c0 + m16;
      C[base] = acc[mi][0][r]; C[base + 16] = acc[mi][1][r];
      C[base + 32] = acc[mi][2][r]; C[base + 48] = acc[mi][3][r];
    }
}

// ---------------- flash attention (causal GQA), fixed-max softmax ----------------
// (unchanged — verified passing at 49.5 us)
__global__ __launch_bounds__(256) void attn_k(const bhalf* __restrict__ q,
                                              const bhalf* __restrict__ k,
                                              const bhalf* __restrict__ vt,
                                              bhalf* __restrict__ o) {
  __shared__ __align__(16) bhalf Kb[2][4096];
  __shared__ __align__(16) bhalf Vb[2][4096];
  __shared__ __align__(16) bhalf Pb[4][16][64];
  int tid = threadIdx.x, lane = tid & 63, w = tid >> 6;
  int h = blockIdx.x, kh = h >> 2;
  int qt = 31 - blockIdx.y;
  int qb = qt * 64;
  int m16 = lane & 15, q4 = lane >> 4;
  int wrow0 = qb + w * 16;

  const bhalf* qp = q + (size_t)(wrow0 + m16) * 2048 + h * 64;
  bhalf8 qf0 = *(const bhalf8*)(qp + q4 * 8);
  bhalf8 qf1 = *(const bhalf8*)(qp + 32 + q4 * 8);

  int srow = tid >> 3;
  int scol = ((tid & 7) ^ (srow & 7)) * 8;
  const bhalf* ksrc = k + (size_t)srow * 512 + kh * 64 + scol;
  const bhalf* vsrc = vt + (size_t)(kh * 64 + srow) * 2048 + scol;
  bhalf* kdst = &Kb[0][0] + w * 512;
  bhalf* vdst = &Vb[0][0] + w * 512;

  auto stage = [&](int c) {
    int buf = c & 1, s0 = c * 64;
#pragma unroll
    for (int j = 0; j < 2; ++j) {
      __builtin_amdgcn_global_load_lds((gas_p)(ksrc + (size_t)(s0 + j * 32) * 512),
                                       (las_p)(kdst + buf * 4096 + j * 2048), 16, 0, 0);
      __builtin_amdgcn_global_load_lds((gas_p)(vsrc + (size_t)(j * 32) * 2048 + s0),
                                       (las_p)(vdst + buf * 4096 + j * 2048), 16, 0, 0);
    }
  };

  f32x4 zero4 = {0.f, 0.f, 0.f, 0.f};
  f32x4 oac[4];
  float psum = 0.f;
#pragma unroll
  for (int ni = 0; ni < 4; ++ni) oac[ni] = zero4;
  int swz = m16 & 7;
  bhalf* prow = &Pb[w][m16][0];
  int woff = (q4 & 1) << 2;

  stage(0);
  for (int c = 0; c <= qt; ++c) {
    __syncthreads();
    if (c < qt) stage(c + 1);
    int buf = c & 1;
    if (c < qt) {
      bhalf8 kf[4][2];
#pragma unroll
      for (int st = 0; st < 4; ++st)
#pragma unroll
        for (int ks = 0; ks < 2; ++ks)
          kf[st][ks] = *(const bhalf8*)&Kb[buf][(st * 16 + m16) * 64 + (((ks * 4 + q4) ^ swz) * 8)];
      f32x4 sv[4];
      __builtin_amdgcn_s_setprio(1);
#pragma unroll
      for (int st = 0; st < 4; ++st) {
        f32x4 t0 = __builtin_amdgcn_mfma_f32_16x16x32_bf16(kf[st][0], qf0, zero4, 0, 0, 0);
        sv[st] = __builtin_amdgcn_mfma_f32_16x16x32_bf16(kf[st][1], qf1, t0, 0, 0, 0);
      }
      __builtin_amdgcn_s_setprio(0);
#pragma unroll
      for (int st = 0; st < 4; ++st) {
        bhalf4 pk;
#pragma unroll
        for (int r = 0; r < 4; ++r) {
          float pe = exp2f(sv[st][r]);
          psum += pe;
          pk[r] = (bhalf)pe;
        }
        *(bhalf4*)(prow + ((((2 * st + (q4 >> 1)) ^ swz) << 3) + woff)) = pk;
      }
      bhalf8 vf[4][2];
#pragma unroll
      for (int ni = 0; ni < 4; ++ni)
#pragma unroll
        for (int ks = 0; ks < 2; ++ks)
          vf[ni][ks] = *(const bhalf8*)&Vb[buf][(ni * 16 + m16) * 64 + (((ks * 4 + q4) ^ swz) * 8)];
      bhalf8 ap0 = *(const bhalf8*)(prow + ((q4 ^ swz) << 3));
      bhalf8 ap1 = *(const bhalf8*)(prow + (((4 + q4) ^ swz) << 3));
      __builtin_amdgcn_s_setprio(1);
#pragma unroll
      for (int ni = 0; ni < 4; ++ni) {
        oac[ni] = __builtin_amdgcn_mfma_f32_16x16x32_bf16(ap0, vf[ni][0], oac[ni], 0, 0, 0);
        oac[ni] = __builtin_amdgcn_mfma_f32_16x16x32_bf16(ap1, vf[ni][1], oac[ni], 0, 0, 0);
      }
      __builtin_amdgcn_s_setprio(0);
    } else {
      bhalf8 kf[4][2];
      f32x4 sv[4];
#pragma unroll
      for (int st = 0; st < 4; ++st)
        if (st <= w) {
#pragma unroll
          for (int ks = 0; ks < 2; ++ks)
            kf[st][ks] = *(const bhalf8*)&Kb[buf][(st * 16 + m16) * 64 + (((ks * 4 + q4) ^ swz) * 8)];
          f32x4 t0 = __builtin_amdgcn_mfma_f32_16x16x32_bf16(kf[st][0], qf0, zero4, 0, 0, 0);
          sv[st] = __builtin_amdgcn_mfma_f32_16x16x32_bf16(kf[st][1], qf1, t0, 0, 0, 0);
        }
      int stwr = (w >= 2) ? 3 : 1;
#pragma unroll
      for (int st = 0; st < 4; ++st) {
        if (st > stwr) continue;
        bhalf4 pk;
#pragma unroll
        for (int r = 0; r < 4; ++r) {
          float pe = 0.f;
          if (st < w) {
            pe = exp2f(sv[st][r]);
          } else if (st == w) {
            pe = (q4 * 4 + r <= m16) ? exp2f(sv[st][r]) : 0.f;
          }
          psum += pe;
          pk[r] = (bhalf)pe;
        }
        *(bhalf4*)(prow + ((((2 * st + (q4 >> 1)) ^ swz) << 3) + woff)) = pk;
      }
      int ksmax = (w >= 2) ? 1 : 0;
      bhalf8 vf[4][2];
#pragma unroll
      for (int ni = 0; ni < 4; ++ni)
#pragma unroll
        for (int ks = 0; ks < 2; ++ks)
          if (ks <= ksmax)
            vf[ni][ks] = *(const bhalf8*)&Vb[buf][(ni * 16 + m16) * 64 + (((ks * 4 + q4) ^ swz) * 8)];
      bhalf8 ap0 = *(const bhalf8*)(prow + ((q4 ^ swz) << 3));
#pragma unroll
      for (int ni = 0; ni < 4; ++ni)
        oac[ni] = __builtin_amdgcn_mfma_f32_16x16x32_bf16(ap0, vf[ni][0], oac[ni], 0, 0, 0);
      if (ksmax) {
        bhalf8 ap1 = *(const bhalf8*)(prow + (((4 + q4) ^ swz) << 3));
#pragma unroll
        for (int ni = 0; ni < 4; ++ni)
          oac[ni] = __builtin_amdgcn_mfma_f32_16x16x32_bf16(ap1, vf[ni][1], oac[ni], 0, 0, 0);
      }
    }
  }
  psum += __shfl_xor(psum, 16);
  psum += __shfl_xor(psum, 32);
  float inv = 1.0f / psum;
  float invr[4];
#pragma unroll
  for (int r = 0; r < 4; ++r) invr[r] = __shfl(inv, q4 * 4 + r);
#pragma unroll
  for (int ni = 0; ni < 4; ++ni)
#pragma unroll
    for (int r = 0; r < 4; ++r) {
      int trow = wrow0 + q4 * 4 + r;
      o[(size_t)trow * 2048 + h * 64 + ni * 16 + m16] = (bhalf)(oac[ni][r] * invr[r]);
    }
}

extern "C" void kernel_launch(void* const* d_in, const int* in_sizes, int n_in,
                              void* d_out, int out_size, void* d_ws, size_t ws_size,
                              hipStream_t stream) {
  const int* positions = (const int*)d_in[0];
  const float* hidden  = (const float*)d_in[1];
  const float* w_qkv   = (const float*)d_in[2];
  const float* w_out   = (const float*)d_in[3];
  const float* q_ln    = (const float*)d_in[4];
  const float* k_ln    = (const float*)d_in[5];
  float* out = (float*)d_out;

  char* wsp = (char*)d_ws;
  bhalf* hid_bf  = (bhalf*)(wsp);                 //  8,388,608 B
  bhalf* wqkvT   = (bhalf*)(wsp + 8388608);       // 12,582,912 B (3072 x 2048)
  bhalf* woutT   = (bhalf*)(wsp + 20971520);      //  8,388,608 B (2048 x 2048)
  bhalf* q_bf    = (bhalf*)(wsp + 29360128);      //  8,388,608 B
  bhalf* k_bf    = (bhalf*)(wsp + 37748736);      //  2,097,152 B
  bhalf* vt_g    = (bhalf*)(wsp + 41943040);      //  2,097,152 B (written by gemm1)
  bhalf* attn_bf = (bhalf*)(wsp + 44040192);      //  8,388,608 B (ends 52.4 MB)
  // RoPE table (512 KB) aliases the START of attn_bf: consumed by gemm1 BEFORE
  // attn_k writes attn_bf (same stream, sequential) -> no extra workspace.
  float* rope_t  = (float*)(wsp + 44040192);

  prep_k<<<14464, 256, 0, stream>>>(hidden, w_qkv, w_out, positions,
                                    hid_bf, wqkvT, woutT, rope_t);
  gemm1_fused_k<<<384, 256, 0, stream>>>(
      hid_bf, wqkvT, rope_t, q_ln, k_ln, q_bf, k_bf, vt_g);
  attn_k<<<dim3(NQH, 32), 256, 0, stream>>>(q_bf, k_bf, vt_g, attn_bf);
  gemm2_k<<<256, 256, 0, stream>>>(attn_bf, woutT, out);
}

// Round 7
// 215.176 us; speedup vs baseline: 1.6446x; 1.0367x over previous
//
#include <hip/hip_runtime.h>

typedef __bf16 bhalf;
typedef __bf16 bhalf8 __attribute__((ext_vector_type(8)));
typedef __bf16 bhalf4 __attribute__((ext_vector_type(4)));
typedef __bf16 bhalf2 __attribute__((ext_vector_type(2)));
typedef float f32x4 __attribute__((ext_vector_type(4)));

typedef __attribute__((address_space(1))) const void* gas_p;
typedef __attribute__((address_space(3))) void* las_p;

#define T_SEQ 2048
#define HIDN  2048
#define NQH   32
#define NKVH  8
#define DH    64
#define NQKV  3072

// ---------------- fused prep: cast + weight transposes + RoPE table ----------------
// blocks [0,4096): cast hidden fp32->bf16
// blocks [4096,5632): transpose+cast w_qkv (64x64 tiles, 48x32)
// blocks [5632,6656): transpose+cast w_out (64x64 tiles, 32x32)
// blocks [6656,6784): RoPE cos/sin table
__global__ __launch_bounds__(256) void prep_k(const float* __restrict__ hidden,
                                              const float* __restrict__ w_qkv,
                                              const float* __restrict__ w_out,
                                              const int* __restrict__ pos,
                                              bhalf* __restrict__ hid_bf,
                                              bhalf* __restrict__ wqkvT,
                                              bhalf* __restrict__ woutT,
                                              float* __restrict__ rope) {
  __shared__ float tile[64][65];
  int bid = blockIdx.x;
  int tx = threadIdx.x;
  if (bid < 4096) {
    int i = (bid * 256 + tx) * 4;
    float4 v = *(const float4*)(hidden + i);
    bhalf4 o;
    o[0] = (bhalf)v.x; o[1] = (bhalf)v.y; o[2] = (bhalf)v.z; o[3] = (bhalf)v.w;
    *(bhalf4*)(hid_bf + i) = o;
    return;
  }
  if (bid >= 6656) {
    int gid = (bid - 6656) * 256 + tx;   // 32768 = 2048 t x 16 j
    int t = gid >> 4, j = gid & 15;
    float p = (float)pos[t];
    float f0 = exp2f((float)j * -0.6228615177913804f);  // theta^(-j/32)
    float a0 = p * f0, a1 = p * f0 * 0.001f;            // theta^(-16/32) = 1e-3
    float4 cs = {cosf(a0), sinf(a0), cosf(a1), sinf(a1)};
    *(float4*)(rope + (size_t)gid * 4) = cs;
    return;
  }
  const float* in;
  bhalf* out;
  int R, C, bx, by;
  if (bid < 5632) {
    int b2 = bid - 4096;
    in = w_qkv; out = wqkvT; R = HIDN; C = NQKV;
    bx = (b2 % 48) * 64; by = (b2 / 48) * 64;
  } else {
    int b2 = bid - 5632;
    in = w_out; out = woutT; R = HIDN; C = HIDN;
    bx = (b2 % 32) * 64; by = (b2 / 32) * 64;
  }
  // load 64R x 64C fp32: float4/lane, 16 lanes x 16B = 256B per row segment
#pragma unroll
  for (int p = 0; p < 4; ++p) {
    int row = p * 16 + (tx >> 4);
    int col = (tx & 15) * 4;
    float4 v = *(const float4*)(in + (size_t)(by + row) * C + bx + col);
    tile[row][col] = v.x; tile[row][col + 1] = v.y;
    tile[row][col + 2] = v.z; tile[row][col + 3] = v.w;
  }
  __syncthreads();
  // store: out-row c gets 64 r as 32 lanes x bhalf2 (128B contiguous)
  // col reads tile[2rp][c]: bank (2rp + c) & 31 -> 2-way only (free)
#pragma unroll
  for (int p = 0; p < 8; ++p) {
    int c = p * 8 + (tx >> 5);
    int rp = tx & 31;
    bhalf2 o2;
    o2[0] = (bhalf)tile[2 * rp][c];
    o2[1] = (bhalf)tile[2 * rp + 1][c];
    *(bhalf2*)(out + (size_t)(bx + c) * R + by + 2 * rp) = o2;
  }
}

#define MFMA_BF16 __builtin_amdgcn_mfma_f32_16x16x32_bf16

// ---- 128x128 GEMM core, DOUBLE-BUFFERED with compile-time buffer bases.
// K-loop unrolled x2 (K=2048 -> 16 iters): stage next half-K-tile into the
// other buffer before computing the current one. One barrier per K-step;
// the vmcnt(0)+barrier drain is covered by ~771 cyc of ds_read+MFMA.
#define GEMM_STAGE(Aps, Bps, k0)                                               \
  _Pragma("unroll")                                                            \
  for (int c = 0; c < 4; ++c) {                                                \
    __builtin_amdgcn_global_load_lds(                                          \
        (gas_p)(asrc_ + (size_t)(c * 32) * 2048 + (k0)),                       \
        (las_p)(Aps + woff_ + c * 2048), 16, 0, 0);                            \
    __builtin_amdgcn_global_load_lds(                                          \
        (gas_p)(bsrc_ + (size_t)(c * 32) * 2048 + (k0)),                       \
        (las_p)(Bps + woff_ + c * 2048), 16, 0, 0);                            \
  }

#define GEMM_KS(Aps, Bps, ks)                                                  \
  {                                                                            \
    const int co_ = (((ks) * 4 + q4) ^ swz_) * 8;                              \
    bhalf8 af0 = *(const bhalf8*)&Aps[(wm_ +  0 + m16) * 64 + co_];            \
    bhalf8 af1 = *(const bhalf8*)&Aps[(wm_ + 16 + m16) * 64 + co_];            \
    bhalf8 af2 = *(const bhalf8*)&Aps[(wm_ + 32 + m16) * 64 + co_];            \
    bhalf8 af3 = *(const bhalf8*)&Aps[(wm_ + 48 + m16) * 64 + co_];            \
    bhalf8 bf0 = *(const bhalf8*)&Bps[(wn_ +  0 + m16) * 64 + co_];            \
    bhalf8 bf1 = *(const bhalf8*)&Bps[(wn_ + 16 + m16) * 64 + co_];            \
    bhalf8 bf2 = *(const bhalf8*)&Bps[(wn_ + 32 + m16) * 64 + co_];            \
    bhalf8 bf3 = *(const bhalf8*)&Bps[(wn_ + 48 + m16) * 64 + co_];            \
    acc[0][0] = MFMA_BF16(af0, bf0, acc[0][0], 0, 0, 0);                       \
    acc[0][1] = MFMA_BF16(af0, bf1, acc[0][1], 0, 0, 0);                       \
    acc[0][2] = MFMA_BF16(af0, bf2, acc[0][2], 0, 0, 0);                       \
    acc[0][3] = MFMA_BF16(af0, bf3, acc[0][3], 0, 0, 0);                       \
    acc[1][0] = MFMA_BF16(af1, bf0, acc[1][0], 0, 0, 0);                       \
    acc[1][1] = MFMA_BF16(af1, bf1, acc[1][1], 0, 0, 0);                       \
    acc[1][2] = MFMA_BF16(af1, bf2, acc[1][2], 0, 0, 0);                       \
    acc[1][3] = MFMA_BF16(af1, bf3, acc[1][3], 0, 0, 0);                       \
    acc[2][0] = MFMA_BF16(af2, bf0, acc[2][0], 0, 0, 0);                       \
    acc[2][1] = MFMA_BF16(af2, bf1, acc[2][1], 0, 0, 0);                       \
    acc[2][2] = MFMA_BF16(af2, bf2, acc[2][2], 0, 0, 0);                       \
    acc[2][3] = MFMA_BF16(af2, bf3, acc[2][3], 0, 0, 0);                       \
    acc[3][0] = MFMA_BF16(af3, bf0, acc[3][0], 0, 0, 0);                       \
    acc[3][1] = MFMA_BF16(af3, bf1, acc[3][1], 0, 0, 0);                       \
    acc[3][2] = MFMA_BF16(af3, bf2, acc[3][2], 0, 0, 0);                       \
    acc[3][3] = MFMA_BF16(af3, bf3, acc[3][3], 0, 0, 0);                       \
  }

#define GEMM_CORE_128DB(Aptr, Bptr)                                            \
  {                                                                            \
    const int srow_ = tid >> 3;                                                \
    const int scol_ = ((tid & 7) ^ (srow_ & 7)) * 8;                           \
    const bhalf* asrc_ = (Aptr) + (size_t)(bm + srow_) * 2048 + scol_;         \
    const bhalf* bsrc_ = (Bptr) + (size_t)(bn + srow_) * 2048 + scol_;         \
    const int woff_ = wv * 512;                                                \
    const int swz_ = m16 & 7;                                                  \
    const int wm_ = (wv >> 1) * 64, wn_ = (wv & 1) * 64;                       \
    GEMM_STAGE(As0, Bs0, 0)                                                    \
    for (int k0 = 0; k0 < 2048; k0 += 128) {                                   \
      __syncthreads(); /* buf0 landed; prior buf0 reads done */                \
      GEMM_STAGE(As1, Bs1, k0 + 64)  /* k0+64 <= 1984 always valid */          \
      GEMM_KS(As0, Bs0, 0)                                                     \
      GEMM_KS(As0, Bs0, 1)                                                     \
      __syncthreads(); /* buf1 landed; prior buf1 reads done */                \
      if (k0 + 128 < 2048) GEMM_STAGE(As0, Bs0, k0 + 128)                      \
      GEMM_KS(As1, Bs1, 0)                                                     \
      GEMM_KS(As1, Bs1, 1)                                                     \
    }                                                                          \
  }

// ---------------- GEMM1 + fused RMSNorm + RoPE(table) + split + cast + V-transpose --------
__global__ __launch_bounds__(256, 1) void gemm1_fused_k(const bhalf* __restrict__ A,
                                                        const bhalf* __restrict__ Bt,
                                                        const float* __restrict__ rope,
                                                        const float* __restrict__ qw,
                                                        const float* __restrict__ kw,
                                                        bhalf* __restrict__ qo,
                                                        bhalf* __restrict__ ko,
                                                        bhalf* __restrict__ vt) {
  __shared__ __align__(16) bhalf As0[8192], Bs0[8192], As1[8192], Bs1[8192];
  int tid = threadIdx.x, lane = tid & 63, wv = tid >> 6;
  int m16 = lane & 15, q4 = lane >> 4;
  int orig = blockIdx.x;                      // 384 blocks
  int wgid = (orig & 7) * 48 + (orig >> 3);   // bijective XCD swizzle (384 = 8*48)
  int bx = wgid % 24, by = wgid / 24;
  int bm = by * 128, bn = bx * 128;
  f32x4 zero4 = {0.f, 0.f, 0.f, 0.f};
  f32x4 acc[4][4];
#pragma unroll
  for (int mi = 0; mi < 4; ++mi)
#pragma unroll
    for (int ni = 0; ni < 4; ++ni) acc[mi][ni] = zero4;

  GEMM_CORE_128DB(A, Bt)

  int r0 = bm + (wv >> 1) * 64;
  int hh = (bn >> 6) + (wv & 1);              // head handled by this wave
  if (hh < 40) {
    float wd[4];
    const float* wptr = (hh < 32) ? qw : kw;
    float wscale = (hh < 32) ? 0.18033688011112042f : 1.0f;  // 0.125*log2(e) for Q
#pragma unroll
    for (int ni = 0; ni < 4; ++ni) wd[ni] = wptr[ni * 16 + m16] * wscale;
#pragma unroll
    for (int mi = 0; mi < 4; ++mi)
#pragma unroll
      for (int r = 0; r < 4; ++r) {
        int trow = r0 + mi * 16 + q4 * 4 + r;
        float x0 = acc[mi][0][r], x1 = acc[mi][1][r], x2 = acc[mi][2][r], x3 = acc[mi][3][r];
        float ss = x0 * x0 + x1 * x1 + x2 * x2 + x3 * x3;
        ss += __shfl_xor(ss, 1);
        ss += __shfl_xor(ss, 2);
        ss += __shfl_xor(ss, 4);
        ss += __shfl_xor(ss, 8);
        float sc = rsqrtf(ss * (1.0f / 64.0f) + 1e-5f);
        float y0 = x0 * sc * wd[0], y1 = x1 * sc * wd[1];
        float y2 = x2 * sc * wd[2], y3 = x3 * sc * wd[3];
        float4 cs = *(const float4*)(rope + ((size_t)trow * 16 + m16) * 4);
        float o0 = y0 * cs.x - y2 * cs.y, o2 = y2 * cs.x + y0 * cs.y;
        float o1 = y1 * cs.z - y3 * cs.w, o3 = y3 * cs.z + y1 * cs.w;
        bhalf* dst = (hh < 32) ? (qo + (size_t)trow * 2048 + hh * 64 + m16)
                               : (ko + (size_t)trow * 512 + (hh - 32) * 64 + m16);
        dst[0] = (bhalf)o0; dst[16] = (bhalf)o1; dst[32] = (bhalf)o2; dst[48] = (bhalf)o3;
      }
  } else {
    // V head: write directly transposed -> vt[(hh-40)*64 + d][t], 4 t's per store
#pragma unroll
    for (int mi = 0; mi < 4; ++mi)
#pragma unroll
      for (int ni = 0; ni < 4; ++ni) {
        int trow0 = r0 + mi * 16 + q4 * 4;
        int d = (hh - 40) * 64 + ni * 16 + m16;
        bhalf4 pk;
        pk[0] = (bhalf)acc[mi][ni][0]; pk[1] = (bhalf)acc[mi][ni][1];
        pk[2] = (bhalf)acc[mi][ni][2]; pk[3] = (bhalf)acc[mi][ni][3];
        *(bhalf4*)(vt + (size_t)d * 2048 + trow0) = pk;
      }
  }
}

// ---------------- GEMM2: plain fp32-out epilogue ----------------
__global__ __launch_bounds__(256, 1) void gemm2_k(const bhalf* __restrict__ A,
                                                  const bhalf* __restrict__ Bt,
                                                  float* __restrict__ C) {
  __shared__ __align__(16) bhalf As0[8192], Bs0[8192], As1[8192], Bs1[8192];
  int tid = threadIdx.x, lane = tid & 63, wv = tid >> 6;
  int m16 = lane & 15, q4 = lane >> 4;
  int orig = blockIdx.x;                      // 256 blocks
  int wgid = (orig & 7) * 32 + (orig >> 3);   // bijective XCD swizzle (256 = 8*32)
  int bx = wgid & 15, by = wgid >> 4;
  int bm = by * 128, bn = bx * 128;
  f32x4 zero4 = {0.f, 0.f, 0.f, 0.f};
  f32x4 acc[4][4];
#pragma unroll
  for (int mi = 0; mi < 4; ++mi)
#pragma unroll
    for (int ni = 0; ni < 4; ++ni) acc[mi][ni] = zero4;

  GEMM_CORE_128DB(A, Bt)

  int r0 = bm + (wv >> 1) * 64;
  int c0 = bn + (wv & 1) * 64;
#pragma unroll
  for (int mi = 0; mi < 4; ++mi)
#pragma unroll
    for (int r = 0; r < 4; ++r) {
      size_t base = (size_t)(r0 + mi * 16 + q4 * 4 + r) * 2048 + c0 + m16;
      C[base] = acc[mi][0][r]; C[base + 16] = acc[mi][1][r];
      C[base + 32] = acc[mi][2][r]; C[base + 48] = acc[mi][3][r];
    }
}

// ---------------- flash attention (causal GQA), fixed-max softmax ----------------
// (unchanged — verified passing at 49.4 us)
__global__ __launch_bounds__(256) void attn_k(const bhalf* __restrict__ q,
                                              const bhalf* __restrict__ k,
                                              const bhalf* __restrict__ vt,
                                              bhalf* __restrict__ o) {
  __shared__ __align__(16) bhalf Kb[2][4096];
  __shared__ __align__(16) bhalf Vb[2][4096];
  __shared__ __align__(16) bhalf Pb[4][16][64];
  int tid = threadIdx.x, lane = tid & 63, w = tid >> 6;
  int h = blockIdx.x, kh = h >> 2;
  int qt = 31 - blockIdx.y;
  int qb = qt * 64;
  int m16 = lane & 15, q4 = lane >> 4;
  int wrow0 = qb + w * 16;

  const bhalf* qp = q + (size_t)(wrow0 + m16) * 2048 + h * 64;
  bhalf8 qf0 = *(const bhalf8*)(qp + q4 * 8);
  bhalf8 qf1 = *(const bhalf8*)(qp + 32 + q4 * 8);

  int srow = tid >> 3;
  int scol = ((tid & 7) ^ (srow & 7)) * 8;
  const bhalf* ksrc = k + (size_t)srow * 512 + kh * 64 + scol;
  const bhalf* vsrc = vt + (size_t)(kh * 64 + srow) * 2048 + scol;
  bhalf* kdst = &Kb[0][0] + w * 512;
  bhalf* vdst = &Vb[0][0] + w * 512;

  auto stage = [&](int c) {
    int buf = c & 1, s0 = c * 64;
#pragma unroll
    for (int j = 0; j < 2; ++j) {
      __builtin_amdgcn_global_load_lds((gas_p)(ksrc + (size_t)(s0 + j * 32) * 512),
                                       (las_p)(kdst + buf * 4096 + j * 2048), 16, 0, 0);
      __builtin_amdgcn_global_load_lds((gas_p)(vsrc + (size_t)(j * 32) * 2048 + s0),
                                       (las_p)(vdst + buf * 4096 + j * 2048), 16, 0, 0);
    }
  };

  f32x4 zero4 = {0.f, 0.f, 0.f, 0.f};
  f32x4 oac[4];
  float psum = 0.f;
#pragma unroll
  for (int ni = 0; ni < 4; ++ni) oac[ni] = zero4;
  int swz = m16 & 7;
  bhalf* prow = &Pb[w][m16][0];
  int woff = (q4 & 1) << 2;

  stage(0);
  for (int c = 0; c <= qt; ++c) {
    __syncthreads();
    if (c < qt) stage(c + 1);
    int buf = c & 1;
    if (c < qt) {
      bhalf8 kf[4][2];
#pragma unroll
      for (int st = 0; st < 4; ++st)
#pragma unroll
        for (int ks = 0; ks < 2; ++ks)
          kf[st][ks] = *(const bhalf8*)&Kb[buf][(st * 16 + m16) * 64 + (((ks * 4 + q4) ^ swz) * 8)];
      f32x4 sv[4];
      __builtin_amdgcn_s_setprio(1);
#pragma unroll
      for (int st = 0; st < 4; ++st) {
        f32x4 t0 = __builtin_amdgcn_mfma_f32_16x16x32_bf16(kf[st][0], qf0, zero4, 0, 0, 0);
        sv[st] = __builtin_amdgcn_mfma_f32_16x16x32_bf16(kf[st][1], qf1, t0, 0, 0, 0);
      }
      __builtin_amdgcn_s_setprio(0);
#pragma unroll
      for (int st = 0; st < 4; ++st) {
        bhalf4 pk;
#pragma unroll
        for (int r = 0; r < 4; ++r) {
          float pe = exp2f(sv[st][r]);
          psum += pe;
          pk[r] = (bhalf)pe;
        }
        *(bhalf4*)(prow + ((((2 * st + (q4 >> 1)) ^ swz) << 3) + woff)) = pk;
      }
      bhalf8 vf[4][2];
#pragma unroll
      for (int ni = 0; ni < 4; ++ni)
#pragma unroll
        for (int ks = 0; ks < 2; ++ks)
          vf[ni][ks] = *(const bhalf8*)&Vb[buf][(ni * 16 + m16) * 64 + (((ks * 4 + q4) ^ swz) * 8)];
      bhalf8 ap0 = *(const bhalf8*)(prow + ((q4 ^ swz) << 3));
      bhalf8 ap1 = *(const bhalf8*)(prow + (((4 + q4) ^ swz) << 3));
      __builtin_amdgcn_s_setprio(1);
#pragma unroll
      for (int ni = 0; ni < 4; ++ni) {
        oac[ni] = __builtin_amdgcn_mfma_f32_16x16x32_bf16(ap0, vf[ni][0], oac[ni], 0, 0, 0);
        oac[ni] = __builtin_amdgcn_mfma_f32_16x16x32_bf16(ap1, vf[ni][1], oac[ni], 0, 0, 0);
      }
      __builtin_amdgcn_s_setprio(0);
    } else {
      bhalf8 kf[4][2];
      f32x4 sv[4];
#pragma unroll
      for (int st = 0; st < 4; ++st)
        if (st <= w) {
#pragma unroll
          for (int ks = 0; ks < 2; ++ks)
            kf[st][ks] = *(const bhalf8*)&Kb[buf][(st * 16 + m16) * 64 + (((ks * 4 + q4) ^ swz) * 8)];
          f32x4 t0 = __builtin_amdgcn_mfma_f32_16x16x32_bf16(kf[st][0], qf0, zero4, 0, 0, 0);
          sv[st] = __builtin_amdgcn_mfma_f32_16x16x32_bf16(kf[st][1], qf1, t0, 0, 0, 0);
        }
      int stwr = (w >= 2) ? 3 : 1;
#pragma unroll
      for (int st = 0; st < 4; ++st) {
        if (st > stwr) continue;
        bhalf4 pk;
#pragma unroll
        for (int r = 0; r < 4; ++r) {
          float pe = 0.f;
          if (st < w) {
            pe = exp2f(sv[st][r]);
          } else if (st == w) {
            pe = (q4 * 4 + r <= m16) ? exp2f(sv[st][r]) : 0.f;
          }
          psum += pe;
          pk[r] = (bhalf)pe;
        }
        *(bhalf4*)(prow + ((((2 * st + (q4 >> 1)) ^ swz) << 3) + woff)) = pk;
      }
      int ksmax = (w >= 2) ? 1 : 0;
      bhalf8 vf[4][2];
#pragma unroll
      for (int ni = 0; ni < 4; ++ni)
#pragma unroll
        for (int ks = 0; ks < 2; ++ks)
          if (ks <= ksmax)
            vf[ni][ks] = *(const bhalf8*)&Vb[buf][(ni * 16 + m16) * 64 + (((ks * 4 + q4) ^ swz) * 8)];
      bhalf8 ap0 = *(const bhalf8*)(prow + ((q4 ^ swz) << 3));
#pragma unroll
      for (int ni = 0; ni < 4; ++ni)
        oac[ni] = __builtin_amdgcn_mfma_f32_16x16x32_bf16(ap0, vf[ni][0], oac[ni], 0, 0, 0);
      if (ksmax) {
        bhalf8 ap1 = *(const bhalf8*)(prow + (((4 + q4) ^ swz) << 3));
#pragma unroll
        for (int ni = 0; ni < 4; ++ni)
          oac[ni] = __builtin_amdgcn_mfma_f32_16x16x32_bf16(ap1, vf[ni][1], oac[ni], 0, 0, 0);
      }
    }
  }
  psum += __shfl_xor(psum, 16);
  psum += __shfl_xor(psum, 32);
  float inv = 1.0f / psum;
  float invr[4];
#pragma unroll
  for (int r = 0; r < 4; ++r) invr[r] = __shfl(inv, q4 * 4 + r);
#pragma unroll
  for (int ni = 0; ni < 4; ++ni)
#pragma unroll
    for (int r = 0; r < 4; ++r) {
      int trow = wrow0 + q4 * 4 + r;
      o[(size_t)trow * 2048 + h * 64 + ni * 16 + m16] = (bhalf)(oac[ni][r] * invr[r]);
    }
}

extern "C" void kernel_launch(void* const* d_in, const int* in_sizes, int n_in,
                              void* d_out, int out_size, void* d_ws, size_t ws_size,
                              hipStream_t stream) {
  const int* positions = (const int*)d_in[0];
  const float* hidden  = (const float*)d_in[1];
  const float* w_qkv   = (const float*)d_in[2];
  const float* w_out   = (const float*)d_in[3];
  const float* q_ln    = (const float*)d_in[4];
  const float* k_ln    = (const float*)d_in[5];
  float* out = (float*)d_out;

  char* wsp = (char*)d_ws;
  bhalf* hid_bf  = (bhalf*)(wsp);                 //  8,388,608 B
  bhalf* wqkvT   = (bhalf*)(wsp + 8388608);       // 12,582,912 B (3072 x 2048)
  bhalf* woutT   = (bhalf*)(wsp + 20971520);      //  8,388,608 B (2048 x 2048)
  bhalf* q_bf    = (bhalf*)(wsp + 29360128);      //  8,388,608 B
  bhalf* k_bf    = (bhalf*)(wsp + 37748736);      //  2,097,152 B
  bhalf* vt_g    = (bhalf*)(wsp + 41943040);      //  2,097,152 B (written by gemm1)
  bhalf* attn_bf = (bhalf*)(wsp + 44040192);      //  8,388,608 B (ends 52.4 MB)
  // RoPE table (512 KB) aliases the START of attn_bf: consumed by gemm1 BEFORE
  // attn_k writes attn_bf (same stream, sequential) -> no extra workspace.
  float* rope_t  = (float*)(wsp + 44040192);

  prep_k<<<6784, 256, 0, stream>>>(hidden, w_qkv, w_out, positions,
                                   hid_bf, wqkvT, woutT, rope_t);
  gemm1_fused_k<<<384, 256, 0, stream>>>(
      hid_bf, wqkvT, rope_t, q_ln, k_ln, q_bf, k_bf, vt_g);
  attn_k<<<dim3(NQH, 32), 256, 0, stream>>>(q_bf, k_bf, vt_g, attn_bf);
  gemm2_k<<<256, 256, 0, stream>>>(attn_bf, woutT, out);
}